// Round 7
// baseline (2457.497 us; speedup 1.0000x reference)
//
#include <hip/hip_runtime.h>
#include <hip/hip_fp16.h>

// ---------------------------------------------------------------------------
// GCN 3-layer forward. fp32 accumulate; fp16 message buffer G.
// R1: multi-block scan. R4: fp16 G (agg FETCH at 8-XCD compulsory floor).
// R5/R6: lane-split aggregates, unroll-8; fused scans.
// R7: CSR build via bucketed 2-pass counting sort:
//     append: wave-aggregated atomics -> (dst,src) u64 bucket streams
//     scatter: bucket pinned to one XCD via blockIdx%8 -> col writes merge
//     in that XCD's L2 (kills the ~7-XCD/line write amplification).
// ---------------------------------------------------------------------------

__global__ __launch_bounds__(256)
void deg_kernel(const int* __restrict__ dst, int* __restrict__ cnt, int E) {
  int e = blockIdx.x * 256 + threadIdx.x;
  if (e < E) atomicAdd(&cnt[dst[e]], 1);
}

// Per-block partial sums of cnt (2048/block) + dinv computed on the fly.
__global__ __launch_bounds__(256)
void scan_partial_dinv_kernel(const int* __restrict__ cnt, int* __restrict__ blocksums,
                              float* __restrict__ dinv, int n) {
  __shared__ int sm[256];
  int base = blockIdx.x * 2048 + threadIdx.x * 8;
  int s = 0;
#pragma unroll
  for (int i = 0; i < 8; ++i) {
    int idx = base + i;
    if (idx < n) {
      int c = cnt[idx];
      s += c;
      dinv[idx] = 1.0f / sqrtf((float)c + 1.0f);
    }
  }
  sm[threadIdx.x] = s;
  __syncthreads();
#pragma unroll
  for (int off = 128; off > 0; off >>= 1) {
    if (threadIdx.x < off) sm[threadIdx.x] += sm[threadIdx.x + off];
    __syncthreads();
  }
  if (threadIdx.x == 0) blocksums[blockIdx.x] = sm[0];
}

// Intra-block exclusive scan + internal scan of blocksums -> rowptr, woff.
__global__ __launch_bounds__(256)
void scan_write_kernel(const int* __restrict__ cnt, const int* __restrict__ blocksums,
                       int* __restrict__ rowptr, int* __restrict__ woff,
                       int n, int E, int nb) {
  __shared__ int sm[256];
  __shared__ int bs[256];
  int t = threadIdx.x;
  if (t < nb) bs[t] = blocksums[t];
  __syncthreads();
  if (t == 0) {
    int run = 0;
    for (int i = 0; i < nb; ++i) {
      int v = bs[i];
      bs[i] = run;
      run += v;
    }
  }
  int base = blockIdx.x * 2048 + t * 8;
  int v[8];
  int s = 0;
#pragma unroll
  for (int i = 0; i < 8; ++i) {
    int idx = base + i;
    v[i] = (idx < n) ? cnt[idx] : 0;
    s += v[i];
  }
  sm[t] = s;
  __syncthreads();
#pragma unroll
  for (int off = 1; off < 256; off <<= 1) {
    int u = (t >= off) ? sm[t - off] : 0;
    __syncthreads();
    sm[t] += u;
    __syncthreads();
  }
  int p = bs[blockIdx.x] + (t ? sm[t - 1] : 0);
#pragma unroll
  for (int i = 0; i < 8; ++i) {
    int idx = base + i;
    if (idx < n) {
      rowptr[idx] = p;
      woff[idx] = p;
      p += v[i];
    }
  }
  if (blockIdx.x == 0 && t == 0) rowptr[n] = E;
}

// Pass 1 of bucketed fill: append packed (dst,src) into per-bucket streams.
// Bucket b covers dst in [b<<shift, (b+1)<<shift); base = rowptr[b<<shift].
// Wave-aggregated atomicAdd on gcnt[b]: one atomic per (wave x bucket).
__global__ __launch_bounds__(256)
void append_kernel(const int* __restrict__ src, const int* __restrict__ dst,
                   const int* __restrict__ rowptr, int* __restrict__ gcnt,
                   unsigned long long* __restrict__ buckets, int E, int n,
                   int shift, int nbuck) {
  int e = blockIdx.x * 256 + threadIdx.x;
  int lane = threadIdx.x & 63;
  bool valid = e < E;
  int s = 0, d = 0, b = 0x7fffffff;
  if (valid) {
    s = src[e];
    d = dst[e];
    b = d >> shift;
  }
  unsigned long long rec = ((unsigned long long)(unsigned)d << 32) | (unsigned)s;
  for (int bb = 0; bb < nbuck; ++bb) {
    unsigned long long m = __ballot(b == bb);
    if (m) {
      int leader = __ffsll((long long)m) - 1;
      int cnt = __popcll(m);
      int base = 0;
      if (lane == leader) base = atomicAdd(&gcnt[bb], cnt);
      base = __shfl(base, leader);
      if (b == bb) {
        int pos = __popcll(m & ((1ull << lane) - 1));
        int bucket_base = rowptr[bb << shift];
        buckets[(size_t)bucket_base + base + pos] = rec;
      }
    }
  }
}

// Pass 2: scatter bucket records into col. Bucket b handled only by blocks
// with blockIdx%8==b -> (heuristically) one XCD owns each ~1MB col window,
// so the random 4B writes merge in its L2. Correct regardless of mapping.
__global__ __launch_bounds__(256)
void scatter_kernel(const unsigned long long* __restrict__ buckets,
                    const int* __restrict__ rowptr, int* __restrict__ woff,
                    int* __restrict__ col, int n, int shift, int nbuck,
                    int blocksPerBucket) {
  int b = blockIdx.x & 7;
  if (b >= nbuck) return;
  int g = blockIdx.x >> 3;
  int lo = rowptr[b << shift];
  int hiNode = (b + 1) << shift;
  int hi = rowptr[hiNode < n ? hiNode : n];
  int cnt = hi - lo;
  for (int i = g * 256 + threadIdx.x; i < cnt; i += blocksPerBucket * 256) {
    unsigned long long rec = buckets[(size_t)lo + i];
    int d = (int)(rec >> 32);
    int s = (int)(unsigned)rec;
    int pos = atomicAdd(&woff[d], 1);
    col[pos] = s;
  }
}

// G[r][c] = fp16( dinv[r] * sum_k X[r][k] * W[k][c] ). M=128, K=128.
__global__ __launch_bounds__(256)
void gemm128_kernel(const float* __restrict__ X, const float* __restrict__ W,
                    const float* __restrict__ dinv, __half* __restrict__ G,
                    int nrows) {
  constexpr int BM = 128, BK = 32, TM = 8, TN = 8;
  __shared__ float xs[BK][BM + 4];
  __shared__ float wsh[BK][128];

  int tid = threadIdx.x;
  int row0 = blockIdx.x * BM;
  int tx = tid & 15;
  int ty = tid >> 4;
  int r0 = ty * TM;
  int c0 = tx * TN;

  float acc[TM][TN];
#pragma unroll
  for (int i = 0; i < TM; ++i)
#pragma unroll
    for (int j = 0; j < TN; ++j) acc[i][j] = 0.0f;

  for (int k0 = 0; k0 < 128; k0 += BK) {
#pragma unroll
    for (int t = tid; t < BM * (BK / 4); t += 256) {
      int r = t >> 3;
      int kk = (t & 7) * 4;
      int grow = row0 + r;
      float4 v = make_float4(0.f, 0.f, 0.f, 0.f);
      if (grow < nrows)
        v = *(const float4*)(X + (size_t)grow * 128 + k0 + kk);
      xs[kk + 0][r] = v.x;
      xs[kk + 1][r] = v.y;
      xs[kk + 2][r] = v.z;
      xs[kk + 3][r] = v.w;
    }
#pragma unroll
    for (int t = tid; t < BK * 32; t += 256) {
      int k = t >> 5;
      int c = (t & 31) * 4;
      *(float4*)(&wsh[k][c]) = *(const float4*)(W + (size_t)(k0 + k) * 128 + c);
    }
    __syncthreads();
#pragma unroll 4
    for (int k = 0; k < BK; ++k) {
      float4 a0 = *(const float4*)(&xs[k][r0]);
      float4 a1 = *(const float4*)(&xs[k][r0 + 4]);
      float4 b0 = *(const float4*)(&wsh[k][c0]);
      float4 b1 = *(const float4*)(&wsh[k][c0 + 4]);
      float a[TM] = {a0.x, a0.y, a0.z, a0.w, a1.x, a1.y, a1.z, a1.w};
      float bb[TN] = {b0.x, b0.y, b0.z, b0.w, b1.x, b1.y, b1.z, b1.w};
#pragma unroll
      for (int i = 0; i < TM; ++i)
#pragma unroll
        for (int j = 0; j < TN; ++j) acc[i][j] += a[i] * bb[j];
    }
    __syncthreads();
  }
#pragma unroll
  for (int i = 0; i < TM; ++i) {
    int grow = row0 + r0 + i;
    if (grow < nrows) {
      float s = dinv[grow];
      __half2* gp = (__half2*)(G + (size_t)grow * 128 + c0);
      gp[0] = __floats2half2_rn(s * acc[i][0], s * acc[i][1]);
      gp[1] = __floats2half2_rn(s * acc[i][2], s * acc[i][3]);
      gp[2] = __floats2half2_rn(s * acc[i][4], s * acc[i][5]);
      gp[3] = __floats2half2_rn(s * acc[i][6], s * acc[i][7]);
    }
  }
}

// M=40 GEMM (output layer): BM=128, TM=4 (one b128 A-read), TN=5.
__global__ __launch_bounds__(256)
void gemm40_kernel(const float* __restrict__ X, const float* __restrict__ W,
                   const float* __restrict__ dinv, __half* __restrict__ G,
                   int nrows) {
  constexpr int BM = 128, BK = 32, TM = 4, TN = 5;
  __shared__ float xs[BK][BM + 4];
  __shared__ float wsh[BK][40];

  int tid = threadIdx.x;
  int row0 = blockIdx.x * BM;
  int tx = tid & 7;
  int ty = tid >> 3;
  int r0 = ty * TM;
  int c0 = tx * TN;

  float acc[TM][TN];
#pragma unroll
  for (int i = 0; i < TM; ++i)
#pragma unroll
    for (int j = 0; j < TN; ++j) acc[i][j] = 0.0f;

  for (int k0 = 0; k0 < 128; k0 += BK) {
#pragma unroll
    for (int t = tid; t < BM * (BK / 4); t += 256) {
      int r = t >> 3;
      int kk = (t & 7) * 4;
      int grow = row0 + r;
      float4 v = make_float4(0.f, 0.f, 0.f, 0.f);
      if (grow < nrows)
        v = *(const float4*)(X + (size_t)grow * 128 + k0 + kk);
      xs[kk + 0][r] = v.x;
      xs[kk + 1][r] = v.y;
      xs[kk + 2][r] = v.z;
      xs[kk + 3][r] = v.w;
    }
#pragma unroll
    for (int t = tid; t < BK * 10; t += 256) {
      int k = t / 10;
      int c = (t % 10) * 4;
      *(float4*)(&wsh[k][c]) = *(const float4*)(W + (size_t)(k0 + k) * 40 + c);
    }
    __syncthreads();
#pragma unroll 4
    for (int k = 0; k < BK; ++k) {
      float4 a0 = *(const float4*)(&xs[k][r0]);
      float a[TM] = {a0.x, a0.y, a0.z, a0.w};
      float bb[TN];
#pragma unroll
      for (int j = 0; j < TN; ++j) bb[j] = wsh[k][c0 + j];
#pragma unroll
      for (int i = 0; i < TM; ++i)
#pragma unroll
        for (int j = 0; j < TN; ++j) acc[i][j] += a[i] * bb[j];
    }
    __syncthreads();
  }
#pragma unroll
  for (int i = 0; i < TM; ++i) {
    int grow = row0 + r0 + i;
    if (grow < nrows) {
      float s = dinv[grow];
#pragma unroll
      for (int j = 0; j < TN; ++j)
        G[(size_t)grow * 40 + c0 + j] = __float2half_rn(s * acc[i][j]);
    }
  }
}

// M=128 aggregate, lane-split (2 edges/wave-instr), unroll 8 per half-wave.
template <bool RELU>
__global__ __launch_bounds__(256)
void aggregate128_kernel(const __half* __restrict__ G, const int* __restrict__ rowptr,
                         const int* __restrict__ col, const float* __restrict__ dinv,
                         const float* __restrict__ bias, float* __restrict__ out,
                         int n) {
  int wid = threadIdx.x >> 6;
  int lane = threadIdx.x & 63;
  int node = blockIdx.x * 4 + wid;
  if (node >= n) return;

  int sub = lane >> 5;
  int c = lane & 31;
  const float2* g2 = (const float2*)G;

  int e = rowptr[node];
  int end = rowptr[node + 1];
  float di = dinv[node];

  float ax = 0.f, ay = 0.f, az = 0.f, aw = 0.f;
  if (sub == 0) {
    float2 raw = g2[(size_t)node * 32 + c];
    float2 f0 = __half22float2(*(const __half2*)&raw.x);
    float2 f1 = __half22float2(*(const __half2*)&raw.y);
    ax = f0.x; ay = f0.y; az = f1.x; aw = f1.y;
  }

  int i = e + sub;
  for (; i + 14 < end; i += 16) {
    float2 r[8];
#pragma unroll
    for (int u = 0; u < 8; ++u) {
      int s0 = col[i + 2 * u];
      r[u] = g2[(size_t)s0 * 32 + c];
    }
#pragma unroll
    for (int u = 0; u < 8; ++u) {
      float2 f0 = __half22float2(*(const __half2*)&r[u].x);
      float2 f1 = __half22float2(*(const __half2*)&r[u].y);
      ax += f0.x; ay += f0.y; az += f1.x; aw += f1.y;
    }
  }
  for (; i + 6 < end; i += 8) {
    float2 r[4];
#pragma unroll
    for (int u = 0; u < 4; ++u) {
      int s0 = col[i + 2 * u];
      r[u] = g2[(size_t)s0 * 32 + c];
    }
#pragma unroll
    for (int u = 0; u < 4; ++u) {
      float2 f0 = __half22float2(*(const __half2*)&r[u].x);
      float2 f1 = __half22float2(*(const __half2*)&r[u].y);
      ax += f0.x; ay += f0.y; az += f1.x; aw += f1.y;
    }
  }
  for (; i < end; i += 2) {
    int s0 = col[i];
    float2 r0 = g2[(size_t)s0 * 32 + c];
    float2 f0 = __half22float2(*(const __half2*)&r0.x);
    float2 f1 = __half22float2(*(const __half2*)&r0.y);
    ax += f0.x; ay += f0.y; az += f1.x; aw += f1.y;
  }

  ax += __shfl_xor(ax, 32);
  ay += __shfl_xor(ay, 32);
  az += __shfl_xor(az, 32);
  aw += __shfl_xor(aw, 32);

  if (sub == 0) {
    float4 bb = ((const float4*)bias)[c];
    float ox = di * ax + bb.x;
    float oy = di * ay + bb.y;
    float oz = di * az + bb.z;
    float ow = di * aw + bb.w;
    if (RELU) {
      ox = fmaxf(ox, 0.0f);
      oy = fmaxf(oy, 0.0f);
      oz = fmaxf(oz, 0.0f);
      ow = fmaxf(ow, 0.0f);
    }
    ((float4*)out)[(size_t)node * 32 + c] = make_float4(ox, oy, oz, ow);
  }
}

// M=40 aggregate, 6-way lane-split.
__global__ __launch_bounds__(256)
void aggregate40_kernel(const __half* __restrict__ G, const int* __restrict__ rowptr,
                        const int* __restrict__ col, const float* __restrict__ dinv,
                        const float* __restrict__ bias, float* __restrict__ out,
                        int n) {
  int wid = threadIdx.x >> 6;
  int lane = threadIdx.x & 63;
  int node = blockIdx.x * 4 + wid;
  if (node >= n) return;

  int sub = lane / 10;
  int c = lane % 10;
  const float2* g2 = (const float2*)G;

  int e = rowptr[node];
  int end = rowptr[node + 1];
  float di = dinv[node];

  float ax = 0.f, ay = 0.f, az = 0.f, aw = 0.f;
  if (sub == 0) {
    float2 raw = g2[(size_t)node * 10 + c];
    float2 f0 = __half22float2(*(const __half2*)&raw.x);
    float2 f1 = __half22float2(*(const __half2*)&raw.y);
    ax = f0.x; ay = f0.y; az = f1.x; aw = f1.y;
  }

  if (sub < 6) {
    int i = e + sub;
    for (; i + 11 < end; i += 12) {
      int s0 = col[i];
      int s1 = col[i + 6];
      float2 r0 = g2[(size_t)s0 * 10 + c];
      float2 r1 = g2[(size_t)s1 * 10 + c];
      float2 f0 = __half22float2(*(const __half2*)&r0.x);
      float2 f1 = __half22float2(*(const __half2*)&r0.y);
      float2 f2 = __half22float2(*(const __half2*)&r1.x);
      float2 f3 = __half22float2(*(const __half2*)&r1.y);
      ax += f0.x + f2.x; ay += f0.y + f2.y;
      az += f1.x + f3.x; aw += f1.y + f3.y;
    }
    for (; i < end; i += 6) {
      int s0 = col[i];
      float2 r0 = g2[(size_t)s0 * 10 + c];
      float2 f0 = __half22float2(*(const __half2*)&r0.x);
      float2 f1 = __half22float2(*(const __half2*)&r0.y);
      ax += f0.x; ay += f0.y; az += f1.x; aw += f1.y;
    }
  }

  float bx = __shfl(ax, lane + 30), by = __shfl(ay, lane + 30),
        bz = __shfl(az, lane + 30), bw = __shfl(aw, lane + 30);
  ax += bx; ay += by; az += bz; aw += bw;
  float c1x = __shfl(ax, lane + 10), c1y = __shfl(ay, lane + 10),
        c1z = __shfl(az, lane + 10), c1w = __shfl(aw, lane + 10);
  float c2x = __shfl(ax, lane + 20), c2y = __shfl(ay, lane + 20),
        c2z = __shfl(az, lane + 20), c2w = __shfl(aw, lane + 20);

  if (sub == 0) {
    float sx = ax + c1x + c2x;
    float sy = ay + c1y + c2y;
    float sz = az + c1z + c2z;
    float sw = aw + c1w + c2w;
    float4 bb = ((const float4*)bias)[c];
    float4 o = make_float4(di * sx + bb.x, di * sy + bb.y, di * sz + bb.z,
                           di * sw + bb.w);
    ((float4*)out)[(size_t)node * 10 + c] = o;
  }
}

extern "C" void kernel_launch(void* const* d_in, const int* in_sizes, int n_in,
                              void* d_out, int out_size, void* d_ws, size_t ws_size,
                              hipStream_t stream) {
  const float* x = (const float*)d_in[0];
  const float* W0 = (const float*)d_in[1];
  const float* b0 = (const float*)d_in[2];
  const float* W1 = (const float*)d_in[3];
  const float* b1 = (const float*)d_in[4];
  const float* W2 = (const float*)d_in[5];
  const float* b2 = (const float*)d_in[6];
  const int* ei = (const int*)d_in[7];

  const int N = in_sizes[0] / 128;
  const int E = in_sizes[7] / 2;
  const int* src = ei;
  const int* dst = ei + E;

  char* w = (char*)d_ws;
  size_t off = 0;
  auto alloc = [&](size_t bytes) -> void* {
    void* p = w + off;
    off = (off + bytes + 255) & ~(size_t)255;
    return p;
  };
  int* cnt = (int*)alloc((size_t)(N + 64) * 4);  // cnt[N] + gcnt[<=8] tail
  int* gcnt = cnt + N;
  float* dinv = (float*)alloc((size_t)N * 4);
  int* rowptr = (int*)alloc((size_t)(N + 1) * 4);
  int* woff = (int*)alloc((size_t)N * 4);
  int* col = (int*)alloc((size_t)E * 4);
  int* blocksums = (int*)alloc(4096 * 4);
  unsigned long long* buckets = (unsigned long long*)alloc((size_t)E * 8);
  __half* gbuf = (__half*)alloc((size_t)N * 128 * 2);
  float* hbuf = (float*)alloc((size_t)N * 128 * 4);
  (void)ws_size;

  // bucket shift: smallest shift with <=8 buckets
  int shift = 14;
  while ((((N - 1) >> shift) + 1) > 8) ++shift;
  int nbuck = ((N - 1) >> shift) + 1;  // 7 for N=100k

  hipMemsetAsync(cnt, 0, (size_t)(N + 64) * 4, stream);

  dim3 blk(256);
  int gE = (E + 255) / 256;
  int nScanBlocks = (N + 2047) / 2048;

  deg_kernel<<<gE, blk, 0, stream>>>(dst, cnt, E);
  scan_partial_dinv_kernel<<<nScanBlocks, blk, 0, stream>>>(cnt, blocksums, dinv, N);
  scan_write_kernel<<<nScanBlocks, blk, 0, stream>>>(cnt, blocksums, rowptr, woff, N, E,
                                                     nScanBlocks);
  append_kernel<<<gE, blk, 0, stream>>>(src, dst, rowptr, gcnt, buckets, E, N,
                                        shift, nbuck);
  const int blocksPerBucket = 192;
  scatter_kernel<<<8 * blocksPerBucket, blk, 0, stream>>>(buckets, rowptr, woff, col,
                                                          N, shift, nbuck,
                                                          blocksPerBucket);

  int gGemm = (N + 127) / 128;
  int gAgg = (N + 3) / 4;

  gemm128_kernel<<<gGemm, blk, 0, stream>>>(x, W0, dinv, gbuf, N);
  aggregate128_kernel<true><<<gAgg, blk, 0, stream>>>(gbuf, rowptr, col, dinv, b0, hbuf, N);
  gemm128_kernel<<<gGemm, blk, 0, stream>>>(hbuf, W1, dinv, gbuf, N);
  aggregate128_kernel<true><<<gAgg, blk, 0, stream>>>(gbuf, rowptr, col, dinv, b1, hbuf, N);
  gemm40_kernel<<<gGemm, blk, 0, stream>>>(hbuf, W2, dinv, gbuf, N);
  aggregate40_kernel<<<gAgg, blk, 0, stream>>>(gbuf, rowptr, col, dinv, b2,
                                               (float*)d_out, N);
}

// Round 8
// 838.491 us; speedup vs baseline: 2.9309x; 2.9309x over previous
//
#include <hip/hip_runtime.h>
#include <hip/hip_fp16.h>

// ---------------------------------------------------------------------------
// GCN 3-layer forward. fp32 accumulate; fp16 message buffer G.
// R1: multi-block scan. R4: fp16 G. R5/R6: lane-split agg, fused scans.
// R7 FAILED: bucketed append serialized on one cache line of counters
//            (1894us). Reverted to R6 CSR build (deg + scans + fill P=2).
// R8: feature-sliced aggregate128: slice = blockIdx&7 -> one XCD owns a
//     3.2MB G column-slice (L2-resident) instead of every XCD fetching all
//     25.6MB (the R5 FETCH=192MB floor). Gathers move L3->L2.
// ---------------------------------------------------------------------------

__global__ __launch_bounds__(256)
void deg_kernel(const int* __restrict__ dst, int* __restrict__ cnt, int E) {
  int e = blockIdx.x * 256 + threadIdx.x;
  if (e < E) atomicAdd(&cnt[dst[e]], 1);
}

// Per-block partial sums of cnt (2048/block) + dinv computed on the fly.
__global__ __launch_bounds__(256)
void scan_partial_dinv_kernel(const int* __restrict__ cnt, int* __restrict__ blocksums,
                              float* __restrict__ dinv, int n) {
  __shared__ int sm[256];
  int base = blockIdx.x * 2048 + threadIdx.x * 8;
  int s = 0;
#pragma unroll
  for (int i = 0; i < 8; ++i) {
    int idx = base + i;
    if (idx < n) {
      int c = cnt[idx];
      s += c;
      dinv[idx] = 1.0f / sqrtf((float)c + 1.0f);
    }
  }
  sm[threadIdx.x] = s;
  __syncthreads();
#pragma unroll
  for (int off = 128; off > 0; off >>= 1) {
    if (threadIdx.x < off) sm[threadIdx.x] += sm[threadIdx.x + off];
    __syncthreads();
  }
  if (threadIdx.x == 0) blocksums[blockIdx.x] = sm[0];
}

// Intra-block exclusive scan + internal scan of blocksums -> rowptr, woff.
__global__ __launch_bounds__(256)
void scan_write_kernel(const int* __restrict__ cnt, const int* __restrict__ blocksums,
                       int* __restrict__ rowptr, int* __restrict__ woff,
                       int n, int E, int nb) {
  __shared__ int sm[256];
  __shared__ int bs[256];
  int t = threadIdx.x;
  if (t < nb) bs[t] = blocksums[t];
  __syncthreads();
  if (t == 0) {
    int run = 0;
    for (int i = 0; i < nb; ++i) {
      int v = bs[i];
      bs[i] = run;
      run += v;
    }
  }
  int base = blockIdx.x * 2048 + t * 8;
  int v[8];
  int s = 0;
#pragma unroll
  for (int i = 0; i < 8; ++i) {
    int idx = base + i;
    v[i] = (idx < n) ? cnt[idx] : 0;
    s += v[i];
  }
  sm[t] = s;
  __syncthreads();
#pragma unroll
  for (int off = 1; off < 256; off <<= 1) {
    int u = (t >= off) ? sm[t - off] : 0;
    __syncthreads();
    sm[t] += u;
    __syncthreads();
  }
  int p = bs[blockIdx.x] + (t ? sm[t - 1] : 0);
#pragma unroll
  for (int i = 0; i < 8; ++i) {
    int idx = base + i;
    if (idx < n) {
      rowptr[idx] = p;
      woff[idx] = p;
      p += v[i];
    }
  }
  if (blockIdx.x == 0 && t == 0) rowptr[n] = E;
}

// Phase-filtered counting-sort scatter; col window (~E/P*4B) stays L2-resident.
__global__ __launch_bounds__(256)
void fill_phase_kernel(const int* __restrict__ src, const int* __restrict__ dst,
                       int* __restrict__ woff, int* __restrict__ col, int E,
                       int lo, int hi) {
  int e = blockIdx.x * 256 + threadIdx.x;
  if (e < E) {
    int d = dst[e];
    if (d >= lo && d < hi) {
      int pos = atomicAdd(&woff[d], 1);
      col[pos] = src[e];
    }
  }
}

// G[r][c] = fp16( dinv[r] * sum_k X[r][k] * W[k][c] ). M=128, K=128.
__global__ __launch_bounds__(256)
void gemm128_kernel(const float* __restrict__ X, const float* __restrict__ W,
                    const float* __restrict__ dinv, __half* __restrict__ G,
                    int nrows) {
  constexpr int BM = 128, BK = 32, TM = 8, TN = 8;
  __shared__ float xs[BK][BM + 4];
  __shared__ float wsh[BK][128];

  int tid = threadIdx.x;
  int row0 = blockIdx.x * BM;
  int tx = tid & 15;
  int ty = tid >> 4;
  int r0 = ty * TM;
  int c0 = tx * TN;

  float acc[TM][TN];
#pragma unroll
  for (int i = 0; i < TM; ++i)
#pragma unroll
    for (int j = 0; j < TN; ++j) acc[i][j] = 0.0f;

  for (int k0 = 0; k0 < 128; k0 += BK) {
#pragma unroll
    for (int t = tid; t < BM * (BK / 4); t += 256) {
      int r = t >> 3;
      int kk = (t & 7) * 4;
      int grow = row0 + r;
      float4 v = make_float4(0.f, 0.f, 0.f, 0.f);
      if (grow < nrows)
        v = *(const float4*)(X + (size_t)grow * 128 + k0 + kk);
      xs[kk + 0][r] = v.x;
      xs[kk + 1][r] = v.y;
      xs[kk + 2][r] = v.z;
      xs[kk + 3][r] = v.w;
    }
#pragma unroll
    for (int t = tid; t < BK * 32; t += 256) {
      int k = t >> 5;
      int c = (t & 31) * 4;
      *(float4*)(&wsh[k][c]) = *(const float4*)(W + (size_t)(k0 + k) * 128 + c);
    }
    __syncthreads();
#pragma unroll 4
    for (int k = 0; k < BK; ++k) {
      float4 a0 = *(const float4*)(&xs[k][r0]);
      float4 a1 = *(const float4*)(&xs[k][r0 + 4]);
      float4 b0 = *(const float4*)(&wsh[k][c0]);
      float4 b1 = *(const float4*)(&wsh[k][c0 + 4]);
      float a[TM] = {a0.x, a0.y, a0.z, a0.w, a1.x, a1.y, a1.z, a1.w};
      float bb[TN] = {b0.x, b0.y, b0.z, b0.w, b1.x, b1.y, b1.z, b1.w};
#pragma unroll
      for (int i = 0; i < TM; ++i)
#pragma unroll
        for (int j = 0; j < TN; ++j) acc[i][j] += a[i] * bb[j];
    }
    __syncthreads();
  }
#pragma unroll
  for (int i = 0; i < TM; ++i) {
    int grow = row0 + r0 + i;
    if (grow < nrows) {
      float s = dinv[grow];
      __half2* gp = (__half2*)(G + (size_t)grow * 128 + c0);
      gp[0] = __floats2half2_rn(s * acc[i][0], s * acc[i][1]);
      gp[1] = __floats2half2_rn(s * acc[i][2], s * acc[i][3]);
      gp[2] = __floats2half2_rn(s * acc[i][4], s * acc[i][5]);
      gp[3] = __floats2half2_rn(s * acc[i][6], s * acc[i][7]);
    }
  }
}

// M=40 GEMM (output layer): BM=128, TM=4 (one b128 A-read), TN=5.
__global__ __launch_bounds__(256)
void gemm40_kernel(const float* __restrict__ X, const float* __restrict__ W,
                   const float* __restrict__ dinv, __half* __restrict__ G,
                   int nrows) {
  constexpr int BM = 128, BK = 32, TM = 4, TN = 5;
  __shared__ float xs[BK][BM + 4];
  __shared__ float wsh[BK][40];

  int tid = threadIdx.x;
  int row0 = blockIdx.x * BM;
  int tx = tid & 7;
  int ty = tid >> 3;
  int r0 = ty * TM;
  int c0 = tx * TN;

  float acc[TM][TN];
#pragma unroll
  for (int i = 0; i < TM; ++i)
#pragma unroll
    for (int j = 0; j < TN; ++j) acc[i][j] = 0.0f;

  for (int k0 = 0; k0 < 128; k0 += BK) {
#pragma unroll
    for (int t = tid; t < BM * (BK / 4); t += 256) {
      int r = t >> 3;
      int kk = (t & 7) * 4;
      int grow = row0 + r;
      float4 v = make_float4(0.f, 0.f, 0.f, 0.f);
      if (grow < nrows)
        v = *(const float4*)(X + (size_t)grow * 128 + k0 + kk);
      xs[kk + 0][r] = v.x;
      xs[kk + 1][r] = v.y;
      xs[kk + 2][r] = v.z;
      xs[kk + 3][r] = v.w;
    }
#pragma unroll
    for (int t = tid; t < BK * 10; t += 256) {
      int k = t / 10;
      int c = (t % 10) * 4;
      *(float4*)(&wsh[k][c]) = *(const float4*)(W + (size_t)(k0 + k) * 40 + c);
    }
    __syncthreads();
#pragma unroll 4
    for (int k = 0; k < BK; ++k) {
      float4 a0 = *(const float4*)(&xs[k][r0]);
      float a[TM] = {a0.x, a0.y, a0.z, a0.w};
      float bb[TN];
#pragma unroll
      for (int j = 0; j < TN; ++j) bb[j] = wsh[k][c0 + j];
#pragma unroll
      for (int i = 0; i < TM; ++i)
#pragma unroll
        for (int j = 0; j < TN; ++j) acc[i][j] += a[i] * bb[j];
    }
    __syncthreads();
  }
#pragma unroll
  for (int i = 0; i < TM; ++i) {
    int grow = row0 + r0 + i;
    if (grow < nrows) {
      float s = dinv[grow];
#pragma unroll
      for (int j = 0; j < TN; ++j)
        G[(size_t)grow * 40 + c0 + j] = __float2half_rn(s * acc[i][j]);
    }
  }
}

// Feature-sliced M=128 aggregate. slice = blockIdx&7 (rides round-robin
// block->XCD dispatch): blocks of slice s only touch G[:, 16s..16s+16)
// = 3.2MB, L2-resident on one XCD. 8 lanes/node (half2 chunk each),
// 32 nodes/block, unroll-4 gather, fused dinv/bias/relu epilogue.
template <bool RELU>
__global__ __launch_bounds__(256)
void aggregate128_sliced_kernel(const __half* __restrict__ G,
                                const int* __restrict__ rowptr,
                                const int* __restrict__ col,
                                const float* __restrict__ dinv,
                                const float* __restrict__ bias,
                                float* __restrict__ out, int n) {
  int slice = blockIdx.x & 7;
  int nb = blockIdx.x >> 3;
  int grp = threadIdx.x >> 3;      // 32 node-groups per block
  int c = threadIdx.x & 7;         // half2 chunk within 16-feature slice
  int node = nb * 32 + grp;
  if (node >= n) return;

  const __half2* g2 = (const __half2*)G;  // row stride 64 half2
  size_t base = (size_t)slice * 8 + c;

  int e = rowptr[node];
  int end = rowptr[node + 1];

  // self-loop term
  float2 acc = __half22float2(g2[(size_t)node * 64 + base]);

  for (; e + 3 < end; e += 4) {
    int s0 = col[e];
    int s1 = col[e + 1];
    int s2 = col[e + 2];
    int s3 = col[e + 3];
    float2 f0 = __half22float2(g2[(size_t)s0 * 64 + base]);
    float2 f1 = __half22float2(g2[(size_t)s1 * 64 + base]);
    float2 f2 = __half22float2(g2[(size_t)s2 * 64 + base]);
    float2 f3 = __half22float2(g2[(size_t)s3 * 64 + base]);
    acc.x += (f0.x + f1.x) + (f2.x + f3.x);
    acc.y += (f0.y + f1.y) + (f2.y + f3.y);
  }
  for (; e < end; ++e) {
    float2 f0 = __half22float2(g2[(size_t)col[e] * 64 + base]);
    acc.x += f0.x;
    acc.y += f0.y;
  }

  float di = dinv[node];
  float2 bb = *(const float2*)(bias + slice * 16 + c * 2);
  float ox = di * acc.x + bb.x;
  float oy = di * acc.y + bb.y;
  if (RELU) {
    ox = fmaxf(ox, 0.0f);
    oy = fmaxf(oy, 0.0f);
  }
  *(float2*)(out + (size_t)node * 128 + slice * 16 + c * 2) = make_float2(ox, oy);
}

// M=40 aggregate, 6-way lane-split (unchanged from R6).
__global__ __launch_bounds__(256)
void aggregate40_kernel(const __half* __restrict__ G, const int* __restrict__ rowptr,
                        const int* __restrict__ col, const float* __restrict__ dinv,
                        const float* __restrict__ bias, float* __restrict__ out,
                        int n) {
  int wid = threadIdx.x >> 6;
  int lane = threadIdx.x & 63;
  int node = blockIdx.x * 4 + wid;
  if (node >= n) return;

  int sub = lane / 10;
  int c = lane % 10;
  const float2* g2 = (const float2*)G;

  int e = rowptr[node];
  int end = rowptr[node + 1];
  float di = dinv[node];

  float ax = 0.f, ay = 0.f, az = 0.f, aw = 0.f;
  if (sub == 0) {
    float2 raw = g2[(size_t)node * 10 + c];
    float2 f0 = __half22float2(*(const __half2*)&raw.x);
    float2 f1 = __half22float2(*(const __half2*)&raw.y);
    ax = f0.x; ay = f0.y; az = f1.x; aw = f1.y;
  }

  if (sub < 6) {
    int i = e + sub;
    for (; i + 11 < end; i += 12) {
      int s0 = col[i];
      int s1 = col[i + 6];
      float2 r0 = g2[(size_t)s0 * 10 + c];
      float2 r1 = g2[(size_t)s1 * 10 + c];
      float2 f0 = __half22float2(*(const __half2*)&r0.x);
      float2 f1 = __half22float2(*(const __half2*)&r0.y);
      float2 f2 = __half22float2(*(const __half2*)&r1.x);
      float2 f3 = __half22float2(*(const __half2*)&r1.y);
      ax += f0.x + f2.x; ay += f0.y + f2.y;
      az += f1.x + f3.x; aw += f1.y + f3.y;
    }
    for (; i < end; i += 6) {
      int s0 = col[i];
      float2 r0 = g2[(size_t)s0 * 10 + c];
      float2 f0 = __half22float2(*(const __half2*)&r0.x);
      float2 f1 = __half22float2(*(const __half2*)&r0.y);
      ax += f0.x; ay += f0.y; az += f1.x; aw += f1.y;
    }
  }

  float bx = __shfl(ax, lane + 30), by = __shfl(ay, lane + 30),
        bz = __shfl(az, lane + 30), bw = __shfl(aw, lane + 30);
  ax += bx; ay += by; az += bz; aw += bw;
  float c1x = __shfl(ax, lane + 10), c1y = __shfl(ay, lane + 10),
        c1z = __shfl(az, lane + 10), c1w = __shfl(aw, lane + 10);
  float c2x = __shfl(ax, lane + 20), c2y = __shfl(ay, lane + 20),
        c2z = __shfl(az, lane + 20), c2w = __shfl(aw, lane + 20);

  if (sub == 0) {
    float sx = ax + c1x + c2x;
    float sy = ay + c1y + c2y;
    float sz = az + c1z + c2z;
    float sw = aw + c1w + c2w;
    float4 bb = ((const float4*)bias)[c];
    float4 o = make_float4(di * sx + bb.x, di * sy + bb.y, di * sz + bb.z,
                           di * sw + bb.w);
    ((float4*)out)[(size_t)node * 10 + c] = o;
  }
}

extern "C" void kernel_launch(void* const* d_in, const int* in_sizes, int n_in,
                              void* d_out, int out_size, void* d_ws, size_t ws_size,
                              hipStream_t stream) {
  const float* x = (const float*)d_in[0];
  const float* W0 = (const float*)d_in[1];
  const float* b0 = (const float*)d_in[2];
  const float* W1 = (const float*)d_in[3];
  const float* b1 = (const float*)d_in[4];
  const float* W2 = (const float*)d_in[5];
  const float* b2 = (const float*)d_in[6];
  const int* ei = (const int*)d_in[7];

  const int N = in_sizes[0] / 128;
  const int E = in_sizes[7] / 2;
  const int* src = ei;
  const int* dst = ei + E;

  char* w = (char*)d_ws;
  size_t off = 0;
  auto alloc = [&](size_t bytes) -> void* {
    void* p = w + off;
    off = (off + bytes + 255) & ~(size_t)255;
    return p;
  };
  int* cnt = (int*)alloc((size_t)N * 4);
  float* dinv = (float*)alloc((size_t)N * 4);
  int* rowptr = (int*)alloc((size_t)(N + 1) * 4);
  int* woff = (int*)alloc((size_t)N * 4);
  int* col = (int*)alloc((size_t)E * 4);
  int* blocksums = (int*)alloc(4096 * 4);
  __half* gbuf = (__half*)alloc((size_t)N * 128 * 2);
  float* hbuf = (float*)alloc((size_t)N * 128 * 4);
  (void)ws_size;

  hipMemsetAsync(cnt, 0, (size_t)N * 4, stream);

  dim3 blk(256);
  int gE = (E + 255) / 256;
  int nScanBlocks = (N + 2047) / 2048;

  deg_kernel<<<gE, blk, 0, stream>>>(dst, cnt, E);
  scan_partial_dinv_kernel<<<nScanBlocks, blk, 0, stream>>>(cnt, blocksums, dinv, N);
  scan_write_kernel<<<nScanBlocks, blk, 0, stream>>>(cnt, blocksums, rowptr, woff, N, E,
                                                     nScanBlocks);

  const int P = 2;
  int chunk = (N + P - 1) / P;
  for (int p = 0; p < P; ++p) {
    int lo = p * chunk;
    int hi = min(N, lo + chunk);
    fill_phase_kernel<<<gE, blk, 0, stream>>>(src, dst, woff, col, E, lo, hi);
  }

  int gGemm = (N + 127) / 128;
  int gAggS = 8 * ((N + 31) / 32);  // 8 slices x node-blocks
  int gAgg = (N + 3) / 4;

  gemm128_kernel<<<gGemm, blk, 0, stream>>>(x, W0, dinv, gbuf, N);
  aggregate128_sliced_kernel<true><<<gAggS, blk, 0, stream>>>(gbuf, rowptr, col, dinv,
                                                              b0, hbuf, N);
  gemm128_kernel<<<gGemm, blk, 0, stream>>>(hbuf, W1, dinv, gbuf, N);
  aggregate128_sliced_kernel<true><<<gAggS, blk, 0, stream>>>(gbuf, rowptr, col, dinv,
                                                              b1, hbuf, N);
  gemm40_kernel<<<gGemm, blk, 0, stream>>>(hbuf, W2, dinv, gbuf, N);
  aggregate40_kernel<<<gAgg, blk, 0, stream>>>(gbuf, rowptr, col, dinv, b2,
                                               (float*)d_out, N);
}

// Round 9
// 583.979 us; speedup vs baseline: 4.2082x; 1.4358x over previous
//
#include <hip/hip_runtime.h>
#include <hip/hip_fp16.h>

// ---------------------------------------------------------------------------
// GCN 3-layer forward. fp32 accumulate; fp16 message buffer G.
// R1: multi-block scan. R4: fp16 G. R5/R6: lane-split agg, fused scans.
// R7 FAILED: global bucket counters serialize cross-XCD (~26cy/atomic on one
//            line => 1.9ms). R8 FAILED: blockIdx%8->XCD slicing doesn't hold
//            (FETCH 192->657MB). Both reverted.
// R9: agg128 gather widened to 16B/lane, 16 lanes/edge row: 4 edges per
//     wave-load-instr, perfectly coalesced 4x64B per row, U=4 (16 edges in
//     flight); shfl_xor(16|32) combine. CSR build/gemms = R6.
// ---------------------------------------------------------------------------

__global__ __launch_bounds__(256)
void deg_kernel(const int* __restrict__ dst, int* __restrict__ cnt, int E) {
  int e = blockIdx.x * 256 + threadIdx.x;
  if (e < E) atomicAdd(&cnt[dst[e]], 1);
}

// Per-block partial sums of cnt (2048/block) + dinv computed on the fly.
__global__ __launch_bounds__(256)
void scan_partial_dinv_kernel(const int* __restrict__ cnt, int* __restrict__ blocksums,
                              float* __restrict__ dinv, int n) {
  __shared__ int sm[256];
  int base = blockIdx.x * 2048 + threadIdx.x * 8;
  int s = 0;
#pragma unroll
  for (int i = 0; i < 8; ++i) {
    int idx = base + i;
    if (idx < n) {
      int c = cnt[idx];
      s += c;
      dinv[idx] = 1.0f / sqrtf((float)c + 1.0f);
    }
  }
  sm[threadIdx.x] = s;
  __syncthreads();
#pragma unroll
  for (int off = 128; off > 0; off >>= 1) {
    if (threadIdx.x < off) sm[threadIdx.x] += sm[threadIdx.x + off];
    __syncthreads();
  }
  if (threadIdx.x == 0) blocksums[blockIdx.x] = sm[0];
}

// Intra-block exclusive scan + internal scan of blocksums -> rowptr, woff.
__global__ __launch_bounds__(256)
void scan_write_kernel(const int* __restrict__ cnt, const int* __restrict__ blocksums,
                       int* __restrict__ rowptr, int* __restrict__ woff,
                       int n, int E, int nb) {
  __shared__ int sm[256];
  __shared__ int bs[256];
  int t = threadIdx.x;
  if (t < nb) bs[t] = blocksums[t];
  __syncthreads();
  if (t == 0) {
    int run = 0;
    for (int i = 0; i < nb; ++i) {
      int v = bs[i];
      bs[i] = run;
      run += v;
    }
  }
  int base = blockIdx.x * 2048 + t * 8;
  int v[8];
  int s = 0;
#pragma unroll
  for (int i = 0; i < 8; ++i) {
    int idx = base + i;
    v[i] = (idx < n) ? cnt[idx] : 0;
    s += v[i];
  }
  sm[t] = s;
  __syncthreads();
#pragma unroll
  for (int off = 1; off < 256; off <<= 1) {
    int u = (t >= off) ? sm[t - off] : 0;
    __syncthreads();
    sm[t] += u;
    __syncthreads();
  }
  int p = bs[blockIdx.x] + (t ? sm[t - 1] : 0);
#pragma unroll
  for (int i = 0; i < 8; ++i) {
    int idx = base + i;
    if (idx < n) {
      rowptr[idx] = p;
      woff[idx] = p;
      p += v[i];
    }
  }
  if (blockIdx.x == 0 && t == 0) rowptr[n] = E;
}

// Phase-filtered counting-sort scatter; col window stays cache-resident.
__global__ __launch_bounds__(256)
void fill_phase_kernel(const int* __restrict__ src, const int* __restrict__ dst,
                       int* __restrict__ woff, int* __restrict__ col, int E,
                       int lo, int hi) {
  int e = blockIdx.x * 256 + threadIdx.x;
  if (e < E) {
    int d = dst[e];
    if (d >= lo && d < hi) {
      int pos = atomicAdd(&woff[d], 1);
      col[pos] = src[e];
    }
  }
}

// G[r][c] = fp16( dinv[r] * sum_k X[r][k] * W[k][c] ). M=128, K=128.
__global__ __launch_bounds__(256)
void gemm128_kernel(const float* __restrict__ X, const float* __restrict__ W,
                    const float* __restrict__ dinv, __half* __restrict__ G,
                    int nrows) {
  constexpr int BM = 128, BK = 32, TM = 8, TN = 8;
  __shared__ float xs[BK][BM + 4];
  __shared__ float wsh[BK][128];

  int tid = threadIdx.x;
  int row0 = blockIdx.x * BM;
  int tx = tid & 15;
  int ty = tid >> 4;
  int r0 = ty * TM;
  int c0 = tx * TN;

  float acc[TM][TN];
#pragma unroll
  for (int i = 0; i < TM; ++i)
#pragma unroll
    for (int j = 0; j < TN; ++j) acc[i][j] = 0.0f;

  for (int k0 = 0; k0 < 128; k0 += BK) {
#pragma unroll
    for (int t = tid; t < BM * (BK / 4); t += 256) {
      int r = t >> 3;
      int kk = (t & 7) * 4;
      int grow = row0 + r;
      float4 v = make_float4(0.f, 0.f, 0.f, 0.f);
      if (grow < nrows)
        v = *(const float4*)(X + (size_t)grow * 128 + k0 + kk);
      xs[kk + 0][r] = v.x;
      xs[kk + 1][r] = v.y;
      xs[kk + 2][r] = v.z;
      xs[kk + 3][r] = v.w;
    }
#pragma unroll
    for (int t = tid; t < BK * 32; t += 256) {
      int k = t >> 5;
      int c = (t & 31) * 4;
      *(float4*)(&wsh[k][c]) = *(const float4*)(W + (size_t)(k0 + k) * 128 + c);
    }
    __syncthreads();
#pragma unroll 4
    for (int k = 0; k < BK; ++k) {
      float4 a0 = *(const float4*)(&xs[k][r0]);
      float4 a1 = *(const float4*)(&xs[k][r0 + 4]);
      float4 b0 = *(const float4*)(&wsh[k][c0]);
      float4 b1 = *(const float4*)(&wsh[k][c0 + 4]);
      float a[TM] = {a0.x, a0.y, a0.z, a0.w, a1.x, a1.y, a1.z, a1.w};
      float bb[TN] = {b0.x, b0.y, b0.z, b0.w, b1.x, b1.y, b1.z, b1.w};
#pragma unroll
      for (int i = 0; i < TM; ++i)
#pragma unroll
        for (int j = 0; j < TN; ++j) acc[i][j] += a[i] * bb[j];
    }
    __syncthreads();
  }
#pragma unroll
  for (int i = 0; i < TM; ++i) {
    int grow = row0 + r0 + i;
    if (grow < nrows) {
      float s = dinv[grow];
      __half2* gp = (__half2*)(G + (size_t)grow * 128 + c0);
      gp[0] = __floats2half2_rn(s * acc[i][0], s * acc[i][1]);
      gp[1] = __floats2half2_rn(s * acc[i][2], s * acc[i][3]);
      gp[2] = __floats2half2_rn(s * acc[i][4], s * acc[i][5]);
      gp[3] = __floats2half2_rn(s * acc[i][6], s * acc[i][7]);
    }
  }
}

// M=40 GEMM (output layer): BM=128, TM=4 (one b128 A-read), TN=5.
__global__ __launch_bounds__(256)
void gemm40_kernel(const float* __restrict__ X, const float* __restrict__ W,
                   const float* __restrict__ dinv, __half* __restrict__ G,
                   int nrows) {
  constexpr int BM = 128, BK = 32, TM = 4, TN = 5;
  __shared__ float xs[BK][BM + 4];
  __shared__ float wsh[BK][40];

  int tid = threadIdx.x;
  int row0 = blockIdx.x * BM;
  int tx = tid & 7;
  int ty = tid >> 3;
  int r0 = ty * TM;
  int c0 = tx * TN;

  float acc[TM][TN];
#pragma unroll
  for (int i = 0; i < TM; ++i)
#pragma unroll
    for (int j = 0; j < TN; ++j) acc[i][j] = 0.0f;

  for (int k0 = 0; k0 < 128; k0 += BK) {
#pragma unroll
    for (int t = tid; t < BM * (BK / 4); t += 256) {
      int r = t >> 3;
      int kk = (t & 7) * 4;
      int grow = row0 + r;
      float4 v = make_float4(0.f, 0.f, 0.f, 0.f);
      if (grow < nrows)
        v = *(const float4*)(X + (size_t)grow * 128 + k0 + kk);
      xs[kk + 0][r] = v.x;
      xs[kk + 1][r] = v.y;
      xs[kk + 2][r] = v.z;
      xs[kk + 3][r] = v.w;
    }
#pragma unroll
    for (int t = tid; t < BK * 10; t += 256) {
      int k = t / 10;
      int c = (t % 10) * 4;
      *(float4*)(&wsh[k][c]) = *(const float4*)(W + (size_t)(k0 + k) * 40 + c);
    }
    __syncthreads();
#pragma unroll 4
    for (int k = 0; k < BK; ++k) {
      float4 a0 = *(const float4*)(&xs[k][r0]);
      float a[TM] = {a0.x, a0.y, a0.z, a0.w};
      float bb[TN];
#pragma unroll
      for (int j = 0; j < TN; ++j) bb[j] = wsh[k][c0 + j];
#pragma unroll
      for (int i = 0; i < TM; ++i)
#pragma unroll
        for (int j = 0; j < TN; ++j) acc[i][j] += a[i] * bb[j];
    }
    __syncthreads();
  }
#pragma unroll
  for (int i = 0; i < TM; ++i) {
    int grow = row0 + r0 + i;
    if (grow < nrows) {
      float s = dinv[grow];
#pragma unroll
      for (int j = 0; j < TN; ++j)
        G[(size_t)grow * 40 + c0 + j] = __float2half_rn(s * acc[i][j]);
    }
  }
}

// M=128 aggregate, 16B/lane: 16 lanes cover one 256B G row (4x64B coalesced),
// one wave-load covers 4 edges. sub=lane>>4 in {0..3} handles edges at
// stride 4; U=4 main loop = 16 edges in flight/wave. shfl_xor(16|32) combine;
// sub 0 (16 lanes) stores the 512B fp32 out row as 2 float4 each.
template <bool RELU>
__global__ __launch_bounds__(256)
void aggregate128_kernel(const __half* __restrict__ G, const int* __restrict__ rowptr,
                         const int* __restrict__ col, const float* __restrict__ dinv,
                         const float* __restrict__ bias, float* __restrict__ out,
                         int n) {
  int wid = threadIdx.x >> 6;
  int lane = threadIdx.x & 63;
  int node = blockIdx.x * 4 + wid;
  if (node >= n) return;

  int sub = lane >> 4;   // 0..3: which edge of the 4-pack
  int c = lane & 15;     // 16B chunk within 256B row
  const float4* g4 = (const float4*)G;  // row stride = 16 float4

  int e = rowptr[node];
  int end = rowptr[node + 1];
  float di = dinv[node];

  float a0 = 0.f, a1 = 0.f, a2 = 0.f, a3 = 0.f,
        a4 = 0.f, a5 = 0.f, a6 = 0.f, a7 = 0.f;

  auto accum = [&](float4 raw) {
    const __half2* h = (const __half2*)&raw;
    float2 f0 = __half22float2(h[0]);
    float2 f1 = __half22float2(h[1]);
    float2 f2 = __half22float2(h[2]);
    float2 f3 = __half22float2(h[3]);
    a0 += f0.x; a1 += f0.y; a2 += f1.x; a3 += f1.y;
    a4 += f2.x; a5 += f2.y; a6 += f3.x; a7 += f3.y;
  };

  if (sub == 0) accum(g4[(size_t)node * 16 + c]);  // self-loop once

  int base = e;
  // main: 16 edges per iteration (4 per sub-group, 4 loads in flight/lane)
  for (; base + 16 <= end; base += 16) {
    float4 r0 = g4[(size_t)col[base + sub] * 16 + c];
    float4 r1 = g4[(size_t)col[base + sub + 4] * 16 + c];
    float4 r2 = g4[(size_t)col[base + sub + 8] * 16 + c];
    float4 r3 = g4[(size_t)col[base + sub + 12] * 16 + c];
    accum(r0);
    accum(r1);
    accum(r2);
    accum(r3);
  }
  // tail: 4 edges per iteration
  for (; base + 4 <= end; base += 4) {
    accum(g4[(size_t)col[base + sub] * 16 + c]);
  }
  // final <4 edges: per-lane predicated
  if (base + sub < end) {
    accum(g4[(size_t)col[base + sub] * 16 + c]);
  }

  // combine the 4 sub-groups
  a0 += __shfl_xor(a0, 16); a1 += __shfl_xor(a1, 16);
  a2 += __shfl_xor(a2, 16); a3 += __shfl_xor(a3, 16);
  a4 += __shfl_xor(a4, 16); a5 += __shfl_xor(a5, 16);
  a6 += __shfl_xor(a6, 16); a7 += __shfl_xor(a7, 16);
  a0 += __shfl_xor(a0, 32); a1 += __shfl_xor(a1, 32);
  a2 += __shfl_xor(a2, 32); a3 += __shfl_xor(a3, 32);
  a4 += __shfl_xor(a4, 32); a5 += __shfl_xor(a5, 32);
  a6 += __shfl_xor(a6, 32); a7 += __shfl_xor(a7, 32);

  if (sub == 0) {
    const float4* b4 = (const float4*)bias;
    float4 bb0 = b4[c * 2];
    float4 bb1 = b4[c * 2 + 1];
    float4 o0 = make_float4(di * a0 + bb0.x, di * a1 + bb0.y,
                            di * a2 + bb0.z, di * a3 + bb0.w);
    float4 o1 = make_float4(di * a4 + bb1.x, di * a5 + bb1.y,
                            di * a6 + bb1.z, di * a7 + bb1.w);
    if (RELU) {
      o0.x = fmaxf(o0.x, 0.f); o0.y = fmaxf(o0.y, 0.f);
      o0.z = fmaxf(o0.z, 0.f); o0.w = fmaxf(o0.w, 0.f);
      o1.x = fmaxf(o1.x, 0.f); o1.y = fmaxf(o1.y, 0.f);
      o1.z = fmaxf(o1.z, 0.f); o1.w = fmaxf(o1.w, 0.f);
    }
    float4* op = (float4*)(out + (size_t)node * 128 + c * 8);
    op[0] = o0;
    op[1] = o1;
  }
}

// M=40 aggregate, 6-way lane-split (R6).
__global__ __launch_bounds__(256)
void aggregate40_kernel(const __half* __restrict__ G, const int* __restrict__ rowptr,
                        const int* __restrict__ col, const float* __restrict__ dinv,
                        const float* __restrict__ bias, float* __restrict__ out,
                        int n) {
  int wid = threadIdx.x >> 6;
  int lane = threadIdx.x & 63;
  int node = blockIdx.x * 4 + wid;
  if (node >= n) return;

  int sub = lane / 10;
  int c = lane % 10;
  const float2* g2 = (const float2*)G;

  int e = rowptr[node];
  int end = rowptr[node + 1];
  float di = dinv[node];

  float ax = 0.f, ay = 0.f, az = 0.f, aw = 0.f;
  if (sub == 0) {
    float2 raw = g2[(size_t)node * 10 + c];
    float2 f0 = __half22float2(*(const __half2*)&raw.x);
    float2 f1 = __half22float2(*(const __half2*)&raw.y);
    ax = f0.x; ay = f0.y; az = f1.x; aw = f1.y;
  }

  if (sub < 6) {
    int i = e + sub;
    for (; i + 11 < end; i += 12) {
      int s0 = col[i];
      int s1 = col[i + 6];
      float2 r0 = g2[(size_t)s0 * 10 + c];
      float2 r1 = g2[(size_t)s1 * 10 + c];
      float2 f0 = __half22float2(*(const __half2*)&r0.x);
      float2 f1 = __half22float2(*(const __half2*)&r0.y);
      float2 f2 = __half22float2(*(const __half2*)&r1.x);
      float2 f3 = __half22float2(*(const __half2*)&r1.y);
      ax += f0.x + f2.x; ay += f0.y + f2.y;
      az += f1.x + f3.x; aw += f1.y + f3.y;
    }
    for (; i < end; i += 6) {
      int s0 = col[i];
      float2 r0 = g2[(size_t)s0 * 10 + c];
      float2 f0 = __half22float2(*(const __half2*)&r0.x);
      float2 f1 = __half22float2(*(const __half2*)&r0.y);
      ax += f0.x; ay += f0.y; az += f1.x; aw += f1.y;
    }
  }

  float bx = __shfl(ax, lane + 30), by = __shfl(ay, lane + 30),
        bz = __shfl(az, lane + 30), bw = __shfl(aw, lane + 30);
  ax += bx; ay += by; az += bz; aw += bw;
  float c1x = __shfl(ax, lane + 10), c1y = __shfl(ay, lane + 10),
        c1z = __shfl(az, lane + 10), c1w = __shfl(aw, lane + 10);
  float c2x = __shfl(ax, lane + 20), c2y = __shfl(ay, lane + 20),
        c2z = __shfl(az, lane + 20), c2w = __shfl(aw, lane + 20);

  if (sub == 0) {
    float sx = ax + c1x + c2x;
    float sy = ay + c1y + c2y;
    float sz = az + c1z + c2z;
    float sw = aw + c1w + c2w;
    float4 bb = ((const float4*)bias)[c];
    float4 o = make_float4(di * sx + bb.x, di * sy + bb.y, di * sz + bb.z,
                           di * sw + bb.w);
    ((float4*)out)[(size_t)node * 10 + c] = o;
  }
}

extern "C" void kernel_launch(void* const* d_in, const int* in_sizes, int n_in,
                              void* d_out, int out_size, void* d_ws, size_t ws_size,
                              hipStream_t stream) {
  const float* x = (const float*)d_in[0];
  const float* W0 = (const float*)d_in[1];
  const float* b0 = (const float*)d_in[2];
  const float* W1 = (const float*)d_in[3];
  const float* b1 = (const float*)d_in[4];
  const float* W2 = (const float*)d_in[5];
  const float* b2 = (const float*)d_in[6];
  const int* ei = (const int*)d_in[7];

  const int N = in_sizes[0] / 128;
  const int E = in_sizes[7] / 2;
  const int* src = ei;
  const int* dst = ei + E;

  char* w = (char*)d_ws;
  size_t off = 0;
  auto alloc = [&](size_t bytes) -> void* {
    void* p = w + off;
    off = (off + bytes + 255) & ~(size_t)255;
    return p;
  };
  int* cnt = (int*)alloc((size_t)N * 4);
  float* dinv = (float*)alloc((size_t)N * 4);
  int* rowptr = (int*)alloc((size_t)(N + 1) * 4);
  int* woff = (int*)alloc((size_t)N * 4);
  int* col = (int*)alloc((size_t)E * 4);
  int* blocksums = (int*)alloc(4096 * 4);
  __half* gbuf = (__half*)alloc((size_t)N * 128 * 2);
  float* hbuf = (float*)alloc((size_t)N * 128 * 4);
  (void)ws_size;

  hipMemsetAsync(cnt, 0, (size_t)N * 4, stream);

  dim3 blk(256);
  int gE = (E + 255) / 256;
  int nScanBlocks = (N + 2047) / 2048;

  deg_kernel<<<gE, blk, 0, stream>>>(dst, cnt, E);
  scan_partial_dinv_kernel<<<nScanBlocks, blk, 0, stream>>>(cnt, blocksums, dinv, N);
  scan_write_kernel<<<nScanBlocks, blk, 0, stream>>>(cnt, blocksums, rowptr, woff, N, E,
                                                     nScanBlocks);

  const int P = 2;
  int chunk = (N + P - 1) / P;
  for (int p = 0; p < P; ++p) {
    int lo = p * chunk;
    int hi = min(N, lo + chunk);
    fill_phase_kernel<<<gE, blk, 0, stream>>>(src, dst, woff, col, E, lo, hi);
  }

  int gGemm = (N + 127) / 128;
  int gAgg = (N + 3) / 4;

  gemm128_kernel<<<gGemm, blk, 0, stream>>>(x, W0, dinv, gbuf, N);
  aggregate128_kernel<true><<<gAgg, blk, 0, stream>>>(gbuf, rowptr, col, dinv, b0, hbuf, N);
  gemm128_kernel<<<gGemm, blk, 0, stream>>>(hbuf, W1, dinv, gbuf, N);
  aggregate128_kernel<true><<<gAgg, blk, 0, stream>>>(gbuf, rowptr, col, dinv, b1, hbuf, N);
  gemm40_kernel<<<gGemm, blk, 0, stream>>>(hbuf, W2, dinv, gbuf, N);
  aggregate40_kernel<<<gAgg, blk, 0, stream>>>(gbuf, rowptr, col, dinv, b2,
                                               (float*)d_out, N);
}

// Round 10
// 536.806 us; speedup vs baseline: 4.5780x; 1.0879x over previous
//
#include <hip/hip_runtime.h>
#include <hip/hip_fp16.h>

// ---------------------------------------------------------------------------
// GCN 3-layer forward. fp32 accumulate; fp16 message buffer G.
// R4: fp16 G. R6: fused scans, fill P=2. R9: 16B/lane agg gather (67us,
//     FETCH at 8-XCD compulsory floor; ~13TB/s L2/L3 => at cache-BW ceiling).
// R7/R8 FAILED (journal): global bucket counters serialize cross-XCD;
//     blockIdx%8->XCD mapping does not hold (FETCH 3.4x).
// R10: fat kernel = gemm128 layer-0 + fill phase-0 (independent; VALU-bound
//      GEMM hides latency-bound fill). XOR-swizzled X staging in gemms kills
//      the 4-way LDS write conflict (pad removed; 2-way is free per m136).
// ---------------------------------------------------------------------------

__global__ __launch_bounds__(256)
void deg_kernel(const int* __restrict__ dst, int* __restrict__ cnt, int E) {
  int e = blockIdx.x * 256 + threadIdx.x;
  if (e < E) atomicAdd(&cnt[dst[e]], 1);
}

// Per-block partial sums of cnt (2048/block) + dinv computed on the fly.
__global__ __launch_bounds__(256)
void scan_partial_dinv_kernel(const int* __restrict__ cnt, int* __restrict__ blocksums,
                              float* __restrict__ dinv, int n) {
  __shared__ int sm[256];
  int base = blockIdx.x * 2048 + threadIdx.x * 8;
  int s = 0;
#pragma unroll
  for (int i = 0; i < 8; ++i) {
    int idx = base + i;
    if (idx < n) {
      int c = cnt[idx];
      s += c;
      dinv[idx] = 1.0f / sqrtf((float)c + 1.0f);
    }
  }
  sm[threadIdx.x] = s;
  __syncthreads();
#pragma unroll
  for (int off = 128; off > 0; off >>= 1) {
    if (threadIdx.x < off) sm[threadIdx.x] += sm[threadIdx.x + off];
    __syncthreads();
  }
  if (threadIdx.x == 0) blocksums[blockIdx.x] = sm[0];
}

// Intra-block exclusive scan + internal scan of blocksums -> rowptr, woff.
__global__ __launch_bounds__(256)
void scan_write_kernel(const int* __restrict__ cnt, const int* __restrict__ blocksums,
                       int* __restrict__ rowptr, int* __restrict__ woff,
                       int n, int E, int nb) {
  __shared__ int sm[256];
  __shared__ int bs[256];
  int t = threadIdx.x;
  if (t < nb) bs[t] = blocksums[t];
  __syncthreads();
  if (t == 0) {
    int run = 0;
    for (int i = 0; i < nb; ++i) {
      int v = bs[i];
      bs[i] = run;
      run += v;
    }
  }
  int base = blockIdx.x * 2048 + t * 8;
  int v[8];
  int s = 0;
#pragma unroll
  for (int i = 0; i < 8; ++i) {
    int idx = base + i;
    v[i] = (idx < n) ? cnt[idx] : 0;
    s += v[i];
  }
  sm[t] = s;
  __syncthreads();
#pragma unroll
  for (int off = 1; off < 256; off <<= 1) {
    int u = (t >= off) ? sm[t - off] : 0;
    __syncthreads();
    sm[t] += u;
    __syncthreads();
  }
  int p = bs[blockIdx.x] + (t ? sm[t - 1] : 0);
#pragma unroll
  for (int i = 0; i < 8; ++i) {
    int idx = base + i;
    if (idx < n) {
      rowptr[idx] = p;
      woff[idx] = p;
      p += v[i];
    }
  }
  if (blockIdx.x == 0 && t == 0) rowptr[n] = E;
}

// fill body: edges with dst in [lo,hi) scatter src into col via woff.
__device__ __forceinline__
void fill_body(const int* __restrict__ src, const int* __restrict__ dst,
               int* __restrict__ woff, int* __restrict__ col, int E,
               int lo, int hi, int blk) {
  int e = blk * 256 + threadIdx.x;
  if (e < E) {
    int d = dst[e];
    if (d >= lo && d < hi) {
      int pos = atomicAdd(&woff[d], 1);
      col[pos] = src[e];
    }
  }
}

__global__ __launch_bounds__(256)
void fill_phase_kernel(const int* __restrict__ src, const int* __restrict__ dst,
                       int* __restrict__ woff, int* __restrict__ col, int E,
                       int lo, int hi) {
  fill_body(src, dst, woff, col, E, lo, hi, blockIdx.x);
}

// gemm128 body: G[r][c] = fp16(dinv[r] * sum_k X[r][k]*W[k][c]). M=K=128.
// X tile transposed in LDS with XOR-swizzled column groups:
//   phys col of (k,r) = ((r>>3) ^ ((k>>2)&3))*8 + (r&7)
// -> staging writes 2-way conflicts (free), reads stay aligned b128.
__device__ __forceinline__
void gemm128_body(const float* __restrict__ X, const float* __restrict__ W,
                  const float* __restrict__ dinv, __half* __restrict__ G,
                  int nrows, int blk, float (*xs)[128], float (*wsh)[128]) {
  constexpr int BM = 128, BK = 32, TM = 8, TN = 8;
  int tid = threadIdx.x;
  int row0 = blk * BM;
  int tx = tid & 15;
  int ty = tid >> 4;
  int c0 = tx * TN;

  float acc[TM][TN];
#pragma unroll
  for (int i = 0; i < TM; ++i)
#pragma unroll
    for (int j = 0; j < TN; ++j) acc[i][j] = 0.0f;

  for (int k0 = 0; k0 < 128; k0 += BK) {
#pragma unroll
    for (int t = tid; t < BM * (BK / 4); t += 256) {
      int r = t >> 3;
      int kk = (t & 7) * 4;
      int grow = row0 + r;
      float4 v = make_float4(0.f, 0.f, 0.f, 0.f);
      if (grow < nrows)
        v = *(const float4*)(X + (size_t)grow * 128 + k0 + kk);
      float vv[4] = {v.x, v.y, v.z, v.w};
#pragma unroll
      for (int j = 0; j < 4; ++j) {
        int k = kk + j;
        int pc = (((r >> 3) ^ ((k >> 2) & 3)) << 3) | (r & 7);
        xs[k][pc] = vv[j];
      }
    }
#pragma unroll
    for (int t = tid; t < BK * 32; t += 256) {
      int k = t >> 5;
      int c = (t & 31) * 4;
      *(float4*)(&wsh[k][c]) = *(const float4*)(W + (size_t)(k0 + k) * 128 + c);
    }
    __syncthreads();
#pragma unroll 4
    for (int k = 0; k < BK; ++k) {
      int f = (k >> 2) & 3;
      int pa = ((ty ^ f) << 3);
      float4 a0 = *(const float4*)(&xs[k][pa]);
      float4 a1 = *(const float4*)(&xs[k][pa + 4]);
      float4 b0 = *(const float4*)(&wsh[k][c0]);
      float4 b1 = *(const float4*)(&wsh[k][c0 + 4]);
      float a[TM] = {a0.x, a0.y, a0.z, a0.w, a1.x, a1.y, a1.z, a1.w};
      float bb[TN] = {b0.x, b0.y, b0.z, b0.w, b1.x, b1.y, b1.z, b1.w};
#pragma unroll
      for (int i = 0; i < TM; ++i)
#pragma unroll
        for (int j = 0; j < TN; ++j) acc[i][j] += a[i] * bb[j];
    }
    __syncthreads();
  }
  int r0 = ty * TM;
#pragma unroll
  for (int i = 0; i < TM; ++i) {
    int grow = row0 + r0 + i;
    if (grow < nrows) {
      float s = dinv[grow];
      __half2* gp = (__half2*)(G + (size_t)grow * 128 + c0);
      gp[0] = __floats2half2_rn(s * acc[i][0], s * acc[i][1]);
      gp[1] = __floats2half2_rn(s * acc[i][2], s * acc[i][3]);
      gp[2] = __floats2half2_rn(s * acc[i][4], s * acc[i][5]);
      gp[3] = __floats2half2_rn(s * acc[i][6], s * acc[i][7]);
    }
  }
}

__global__ __launch_bounds__(256)
void gemm128_kernel(const float* __restrict__ X, const float* __restrict__ W,
                    const float* __restrict__ dinv, __half* __restrict__ G,
                    int nrows) {
  __shared__ float xs[32][128];
  __shared__ float wsh[32][128];
  gemm128_body(X, W, dinv, G, nrows, blockIdx.x, xs, wsh);
}

// Fat kernel: blocks [0,gGemm) run gemm128 layer-0; the rest run fill phase-0.
// Independent workloads (gemm: x,W0,dinv -> gbuf; fill: src,dst,woff -> col),
// complementary pipes (VALU vs atomic/write latency).
__global__ __launch_bounds__(256)
void gemm128_fill_kernel(const float* __restrict__ X, const float* __restrict__ W,
                         const float* __restrict__ dinv, __half* __restrict__ G,
                         int nrows, int gGemm,
                         const int* __restrict__ src, const int* __restrict__ dst,
                         int* __restrict__ woff, int* __restrict__ col, int E,
                         int lo, int hi) {
  __shared__ float xs[32][128];
  __shared__ float wsh[32][128];
  if ((int)blockIdx.x < gGemm) {
    gemm128_body(X, W, dinv, G, nrows, blockIdx.x, xs, wsh);
  } else {
    fill_body(src, dst, woff, col, E, lo, hi, blockIdx.x - gGemm);
  }
}

// M=40 GEMM (output layer): BM=128, TM=4, TN=5; same XOR-swizzled X staging.
__global__ __launch_bounds__(256)
void gemm40_kernel(const float* __restrict__ X, const float* __restrict__ W,
                   const float* __restrict__ dinv, __half* __restrict__ G,
                   int nrows) {
  constexpr int BM = 128, BK = 32, TM = 4, TN = 5;
  __shared__ float xs[BK][BM];
  __shared__ float wsh[BK][40];

  int tid = threadIdx.x;
  int row0 = blockIdx.x * BM;
  int tx = tid & 7;    // 8 col groups * 5
  int ty = tid >> 3;   // 32 row groups * 4
  int c0 = tx * TN;

  float acc[TM][TN];
#pragma unroll
  for (int i = 0; i < TM; ++i)
#pragma unroll
    for (int j = 0; j < TN; ++j) acc[i][j] = 0.0f;

  for (int k0 = 0; k0 < 128; k0 += BK) {
#pragma unroll
    for (int t = tid; t < BM * (BK / 4); t += 256) {
      int r = t >> 3;
      int kk = (t & 7) * 4;
      int grow = row0 + r;
      float4 v = make_float4(0.f, 0.f, 0.f, 0.f);
      if (grow < nrows)
        v = *(const float4*)(X + (size_t)grow * 128 + k0 + kk);
      float vv[4] = {v.x, v.y, v.z, v.w};
#pragma unroll
      for (int j = 0; j < 4; ++j) {
        int k = kk + j;
        int pc = (((r >> 3) ^ ((k >> 2) & 3)) << 3) | (r & 7);
        xs[k][pc] = vv[j];
      }
    }
#pragma unroll
    for (int t = tid; t < BK * 10; t += 256) {
      int k = t / 10;
      int c = (t % 10) * 4;
      *(float4*)(&wsh[k][c]) = *(const float4*)(W + (size_t)(k0 + k) * 40 + c);
    }
    __syncthreads();
#pragma unroll 4
    for (int k = 0; k < BK; ++k) {
      int f = (k >> 2) & 3;
      int r0 = ty * TM;
      int pa = ((((r0 >> 3) ^ f)) << 3) | (r0 & 7);
      float4 a0 = *(const float4*)(&xs[k][pa]);
      float a[TM] = {a0.x, a0.y, a0.z, a0.w};
      float bb[TN];
#pragma unroll
      for (int j = 0; j < TN; ++j) bb[j] = wsh[k][c0 + j];
#pragma unroll
      for (int i = 0; i < TM; ++i)
#pragma unroll
        for (int j = 0; j < TN; ++j) acc[i][j] += a[i] * bb[j];
    }
    __syncthreads();
  }
  int r0 = ty * TM;
#pragma unroll
  for (int i = 0; i < TM; ++i) {
    int grow = row0 + r0 + i;
    if (grow < nrows) {
      float s = dinv[grow];
#pragma unroll
      for (int j = 0; j < TN; ++j)
        G[(size_t)grow * 40 + c0 + j] = __float2half_rn(s * acc[i][j]);
    }
  }
}

// M=128 aggregate, 16B/lane: 16 lanes cover one 256B G row (4x64B coalesced),
// one wave-load covers 4 edges; U=4 -> 16 edges in flight/wave.
template <bool RELU>
__global__ __launch_bounds__(256)
void aggregate128_kernel(const __half* __restrict__ G, const int* __restrict__ rowptr,
                         const int* __restrict__ col, const float* __restrict__ dinv,
                         const float* __restrict__ bias, float* __restrict__ out,
                         int n) {
  int wid = threadIdx.x >> 6;
  int lane = threadIdx.x & 63;
  int node = blockIdx.x * 4 + wid;
  if (node >= n) return;

  int sub = lane >> 4;
  int c = lane & 15;
  const float4* g4 = (const float4*)G;  // row stride = 16 float4

  int e = rowptr[node];
  int end = rowptr[node + 1];
  float di = dinv[node];

  float a0 = 0.f, a1 = 0.f, a2 = 0.f, a3 = 0.f,
        a4 = 0.f, a5 = 0.f, a6 = 0.f, a7 = 0.f;

  auto accum = [&](float4 raw) {
    const __half2* h = (const __half2*)&raw;
    float2 f0 = __half22float2(h[0]);
    float2 f1 = __half22float2(h[1]);
    float2 f2 = __half22float2(h[2]);
    float2 f3 = __half22float2(h[3]);
    a0 += f0.x; a1 += f0.y; a2 += f1.x; a3 += f1.y;
    a4 += f2.x; a5 += f2.y; a6 += f3.x; a7 += f3.y;
  };

  if (sub == 0) accum(g4[(size_t)node * 16 + c]);  // self-loop once

  int base = e;
  for (; base + 16 <= end; base += 16) {
    float4 r0 = g4[(size_t)col[base + sub] * 16 + c];
    float4 r1 = g4[(size_t)col[base + sub + 4] * 16 + c];
    float4 r2 = g4[(size_t)col[base + sub + 8] * 16 + c];
    float4 r3 = g4[(size_t)col[base + sub + 12] * 16 + c];
    accum(r0);
    accum(r1);
    accum(r2);
    accum(r3);
  }
  for (; base + 4 <= end; base += 4) {
    accum(g4[(size_t)col[base + sub] * 16 + c]);
  }
  if (base + sub < end) {
    accum(g4[(size_t)col[base + sub] * 16 + c]);
  }

  a0 += __shfl_xor(a0, 16); a1 += __shfl_xor(a1, 16);
  a2 += __shfl_xor(a2, 16); a3 += __shfl_xor(a3, 16);
  a4 += __shfl_xor(a4, 16); a5 += __shfl_xor(a5, 16);
  a6 += __shfl_xor(a6, 16); a7 += __shfl_xor(a7, 16);
  a0 += __shfl_xor(a0, 32); a1 += __shfl_xor(a1, 32);
  a2 += __shfl_xor(a2, 32); a3 += __shfl_xor(a3, 32);
  a4 += __shfl_xor(a4, 32); a5 += __shfl_xor(a5, 32);
  a6 += __shfl_xor(a6, 32); a7 += __shfl_xor(a7, 32);

  if (sub == 0) {
    const float4* b4 = (const float4*)bias;
    float4 bb0 = b4[c * 2];
    float4 bb1 = b4[c * 2 + 1];
    float4 o0 = make_float4(di * a0 + bb0.x, di * a1 + bb0.y,
                            di * a2 + bb0.z, di * a3 + bb0.w);
    float4 o1 = make_float4(di * a4 + bb1.x, di * a5 + bb1.y,
                            di * a6 + bb1.z, di * a7 + bb1.w);
    if (RELU) {
      o0.x = fmaxf(o0.x, 0.f); o0.y = fmaxf(o0.y, 0.f);
      o0.z = fmaxf(o0.z, 0.f); o0.w = fmaxf(o0.w, 0.f);
      o1.x = fmaxf(o1.x, 0.f); o1.y = fmaxf(o1.y, 0.f);
      o1.z = fmaxf(o1.z, 0.f); o1.w = fmaxf(o1.w, 0.f);
    }
    float4* op = (float4*)(out + (size_t)node * 128 + c * 8);
    op[0] = o0;
    op[1] = o1;
  }
}

// M=40 aggregate, 6-way lane-split.
__global__ __launch_bounds__(256)
void aggregate40_kernel(const __half* __restrict__ G, const int* __restrict__ rowptr,
                        const int* __restrict__ col, const float* __restrict__ dinv,
                        const float* __restrict__ bias, float* __restrict__ out,
                        int n) {
  int wid = threadIdx.x >> 6;
  int lane = threadIdx.x & 63;
  int node = blockIdx.x * 4 + wid;
  if (node >= n) return;

  int sub = lane / 10;
  int c = lane % 10;
  const float2* g2 = (const float2*)G;

  int e = rowptr[node];
  int end = rowptr[node + 1];
  float di = dinv[node];

  float ax = 0.f, ay = 0.f, az = 0.f, aw = 0.f;
  if (sub == 0) {
    float2 raw = g2[(size_t)node * 10 + c];
    float2 f0 = __half22float2(*(const __half2*)&raw.x);
    float2 f1 = __half22float2(*(const __half2*)&raw.y);
    ax = f0.x; ay = f0.y; az = f1.x; aw = f1.y;
  }

  if (sub < 6) {
    int i = e + sub;
    for (; i + 11 < end; i += 12) {
      int s0 = col[i];
      int s1 = col[i + 6];
      float2 r0 = g2[(size_t)s0 * 10 + c];
      float2 r1 = g2[(size_t)s1 * 10 + c];
      float2 f0 = __half22float2(*(const __half2*)&r0.x);
      float2 f1 = __half22float2(*(const __half2*)&r0.y);
      float2 f2 = __half22float2(*(const __half2*)&r1.x);
      float2 f3 = __half22float2(*(const __half2*)&r1.y);
      ax += f0.x + f2.x; ay += f0.y + f2.y;
      az += f1.x + f3.x; aw += f1.y + f3.y;
    }
    for (; i < end; i += 6) {
      int s0 = col[i];
      float2 r0 = g2[(size_t)s0 * 10 + c];
      float2 f0 = __half22float2(*(const __half2*)&r0.x);
      float2 f1 = __half22float2(*(const __half2*)&r0.y);
      ax += f0.x; ay += f0.y; az += f1.x; aw += f1.y;
    }
  }

  float bx = __shfl(ax, lane + 30), by = __shfl(ay, lane + 30),
        bz = __shfl(az, lane + 30), bw = __shfl(aw, lane + 30);
  ax += bx; ay += by; az += bz; aw += bw;
  float c1x = __shfl(ax, lane + 10), c1y = __shfl(ay, lane + 10),
        c1z = __shfl(az, lane + 10), c1w = __shfl(aw, lane + 10);
  float c2x = __shfl(ax, lane + 20), c2y = __shfl(ay, lane + 20),
        c2z = __shfl(az, lane + 20), c2w = __shfl(aw, lane + 20);

  if (sub == 0) {
    float sx = ax + c1x + c2x;
    float sy = ay + c1y + c2y;
    float sz = az + c1z + c2z;
    float sw = aw + c1w + c2w;
    float4 bb = ((const float4*)bias)[c];
    float4 o = make_float4(di * sx + bb.x, di * sy + bb.y, di * sz + bb.z,
                           di * sw + bb.w);
    ((float4*)out)[(size_t)node * 10 + c] = o;
  }
}

extern "C" void kernel_launch(void* const* d_in, const int* in_sizes, int n_in,
                              void* d_out, int out_size, void* d_ws, size_t ws_size,
                              hipStream_t stream) {
  const float* x = (const float*)d_in[0];
  const float* W0 = (const float*)d_in[1];
  const float* b0 = (const float*)d_in[2];
  const float* W1 = (const float*)d_in[3];
  const float* b1 = (const float*)d_in[4];
  const float* W2 = (const float*)d_in[5];
  const float* b2 = (const float*)d_in[6];
  const int* ei = (const int*)d_in[7];

  const int N = in_sizes[0] / 128;
  const int E = in_sizes[7] / 2;
  const int* src = ei;
  const int* dst = ei + E;

  char* w = (char*)d_ws;
  size_t off = 0;
  auto alloc = [&](size_t bytes) -> void* {
    void* p = w + off;
    off = (off + bytes + 255) & ~(size_t)255;
    return p;
  };
  int* cnt = (int*)alloc((size_t)N * 4);
  float* dinv = (float*)alloc((size_t)N * 4);
  int* rowptr = (int*)alloc((size_t)(N + 1) * 4);
  int* woff = (int*)alloc((size_t)N * 4);
  int* col = (int*)alloc((size_t)E * 4);
  int* blocksums = (int*)alloc(4096 * 4);
  __half* gbuf = (__half*)alloc((size_t)N * 128 * 2);
  float* hbuf = (float*)alloc((size_t)N * 128 * 4);
  (void)ws_size;

  hipMemsetAsync(cnt, 0, (size_t)N * 4, stream);

  dim3 blk(256);
  int gE = (E + 255) / 256;
  int nScanBlocks = (N + 2047) / 2048;

  deg_kernel<<<gE, blk, 0, stream>>>(dst, cnt, E);
  scan_partial_dinv_kernel<<<nScanBlocks, blk, 0, stream>>>(cnt, blocksums, dinv, N);
  scan_write_kernel<<<nScanBlocks, blk, 0, stream>>>(cnt, blocksums, rowptr, woff, N, E,
                                                     nScanBlocks);

  int gGemm = (N + 127) / 128;
  int gAgg = (N + 3) / 4;
  int half = (N + 1) / 2;

  // FAT: gemm128 layer-0 + fill phase 0 (dst in [0, half))
  gemm128_fill_kernel<<<gGemm + gE, blk, 0, stream>>>(x, W0, dinv, gbuf, N, gGemm,
                                                      src, dst, woff, col, E, 0, half);
  // fill phase 1 (dst in [half, N))
  fill_phase_kernel<<<gE, blk, 0, stream>>>(src, dst, woff, col, E, half, N);

  aggregate128_kernel<true><<<gAgg, blk, 0, stream>>>(gbuf, rowptr, col, dinv, b0, hbuf, N);
  gemm128_kernel<<<gGemm, blk, 0, stream>>>(hbuf, W1, dinv, gbuf, N);
  aggregate128_kernel<true><<<gAgg, blk, 0, stream>>>(gbuf, rowptr, col, dinv, b1, hbuf, N);
  gemm40_kernel<<<gGemm, blk, 0, stream>>>(hbuf, W2, dinv, gbuf, N);
  aggregate40_kernel<<<gAgg, blk, 0, stream>>>(gbuf, rowptr, col, dinv, b2,
                                               (float*)d_out, N);
}